// Round 5
// baseline (481.017 us; speedup 1.0000x reference)
//
#include <hip/hip_runtime.h>

constexpr int N_NODES = 50000;
constexpr int N_EDGES = 800000;
constexpr int D = 64;
constexpr int NB = (N_NODES + 63) / 64;      // 782 buckets of 64 dst nodes

typedef __attribute__((ext_vector_type(8))) short short8;
typedef __attribute__((ext_vector_type(4))) float f32x4;

static __device__ inline unsigned short f2bf(float f) {
    unsigned u = __float_as_uint(f);
    unsigned r = (u + 0x7FFFu + ((u >> 16) & 1u)) >> 16;   // RNE
    return (unsigned short)r;
}
static __device__ inline unsigned pack2(float lo, float hi) {
    return (unsigned)f2bf(lo) | ((unsigned)f2bf(hi) << 16);
}
static __device__ inline float bf2f(unsigned short b) {
    return __uint_as_float((unsigned)b << 16);
}

constexpr unsigned DUMMY_ENT = 64u << 16;    // d=64 (sink row), src=0

// ---------------------------------------------------------------------------
// 1) prep: x fp32 -> bf16 (grid-stride) + bucket histogram (LDS -> global)
// ---------------------------------------------------------------------------
__global__ __launch_bounds__(256) void k_prep(
    const float* __restrict__ x, unsigned short* __restrict__ xb,
    const int* __restrict__ edge_index, unsigned* __restrict__ g_counts)
{
    __shared__ unsigned h[NB];
    int tid = threadIdx.x;
    for (int b = tid; b < NB; b += 256) h[b] = 0u;

    int gid = blockIdx.x * 256 + tid;
    // convert: 800000 uint2 groups (4 floats each)
    for (int t = gid; t < N_NODES * D / 4; t += 65536) {
        float4 v = ((const float4*)x)[t];
        uint2 p;
        p.x = pack2(v.x, v.y);
        p.y = pack2(v.z, v.w);
        ((uint2*)xb)[t] = p;
    }
    __syncthreads();
    for (int t = gid; t < N_EDGES; t += 65536) {
        int col = edge_index[N_EDGES + t];
        atomicAdd(&h[col >> 6], 1u);
    }
    __syncthreads();
    for (int b = tid; b < NB; b += 256) {
        unsigned c = h[b];
        if (c) atomicAdd(&g_counts[b], c);
    }
}

// ---------------------------------------------------------------------------
// 2) scan 782 bucket counts -> bucket_ptr + cursor; pack W -> bf16 B_packed
//    B_packed[n*128 + k]: k<64 = W_self[n][k], k>=64 = W_msg[n][k-64]
// ---------------------------------------------------------------------------
__global__ __launch_bounds__(1024) void k_scan(
    const unsigned* __restrict__ counts,
    unsigned* __restrict__ bucket_ptr, unsigned* __restrict__ cursor,
    const float* __restrict__ W_msg, const float* __restrict__ W_self,
    unsigned short* __restrict__ B_packed)
{
    __shared__ unsigned s[1024];
    int t = threadIdx.x;
    unsigned c = (t < NB) ? counts[t] : 0u;
    s[t] = c;
    __syncthreads();
    for (int off = 1; off < 1024; off <<= 1) {
        unsigned v = (t >= off) ? s[t - off] : 0u;
        __syncthreads();
        s[t] += v;
        __syncthreads();
    }
    if (t < NB) {
        unsigned e = s[t] - c;     // exclusive
        bucket_ptr[t] = e;
        cursor[t] = e;
    }
    if (t == 0) bucket_ptr[NB] = (unsigned)N_EDGES;

    // W packing: 64 x 128 elements
    for (int idx = t; idx < 64 * 128; idx += 1024) {
        int n = idx >> 7;
        int k = idx & 127;
        float v = (k < 64) ? W_self[n * 64 + k] : W_msg[n * 64 + (k - 64)];
        B_packed[idx] = f2bf(v);
    }
}

// ---------------------------------------------------------------------------
// 3) two-pass binning: each block reserves contiguous ranges per bucket,
//    then writes entries (src | dlow<<16) into its private range.
// ---------------------------------------------------------------------------
constexpr int EDGES_PER_BLOCK = (N_EDGES + 255) / 256;   // 3125

__global__ __launch_bounds__(256) void k_bin_place(
    const int* __restrict__ edge_index,
    unsigned* __restrict__ g_cursor, unsigned* __restrict__ bucket_data)
{
    __shared__ unsigned lcount[NB];
    __shared__ unsigned lbase[NB];

    int tid = threadIdx.x;
    int e0 = blockIdx.x * EDGES_PER_BLOCK;
    int e1 = min(e0 + EDGES_PER_BLOCK, N_EDGES);

    for (int b = tid; b < NB; b += 256) lcount[b] = 0u;
    __syncthreads();

    for (int e = e0 + tid; e < e1; e += 256)
        atomicAdd(&lcount[edge_index[N_EDGES + e] >> 6], 1u);
    __syncthreads();

    for (int b = tid; b < NB; b += 256) {
        unsigned c = lcount[b];
        lbase[b] = c ? atomicAdd(&g_cursor[b], c) : 0u;
    }
    __syncthreads();
    for (int b = tid; b < NB; b += 256) lcount[b] = 0u;
    __syncthreads();

    for (int e = e0 + tid; e < e1; e += 256) {
        int dst = edge_index[N_EDGES + e];
        int src = edge_index[e];
        int b = dst >> 6;
        unsigned off = atomicAdd(&lcount[b], 1u);
        bucket_data[lbase[b] + off] = (unsigned)src | ((unsigned)(dst & 63) << 16);
    }
}

// ---------------------------------------------------------------------------
// 4) fused: edge-parallel LDS-atomic gather-mean + bf16 MFMA GEMM.
//    Block = 64 dst nodes (bucket). acc fp32[65][64] unioned with B_sh.
// ---------------------------------------------------------------------------
constexpr int A_STRIDE = 136;   // u16 units; 272B row stride

__global__ __launch_bounds__(256) void k_fused(
    const unsigned short* __restrict__ x_bf16,
    const unsigned short* __restrict__ B_packed,
    const float* __restrict__ b_msg, const float* __restrict__ b_self,
    const unsigned* __restrict__ bucket_ptr,
    const unsigned* __restrict__ bucket_data,
    float* __restrict__ out)
{
    __shared__ __align__(16) unsigned short A_sh[64 * A_STRIDE];
    __shared__ __align__(16) unsigned short ubuf[64 * A_STRIDE];  // acc / B_sh union
    __shared__ unsigned deg[65];

    float* acc = (float*)ubuf;          // 65*64 floats = 16640 B <= 17408 B

    int tid = threadIdx.x;
    int r0 = blockIdx.x * 64;

    // zero acc + deg; stage x rows into A_sh (k<64)
    for (int i = tid; i < 65 * 64; i += 256) acc[i] = 0.0f;
    if (tid < 65) deg[tid] = 0u;
    for (int idx = tid; idx < 64 * 16; idx += 256) {
        int row = idx >> 4;
        int c   = idx & 15;
        int g   = r0 + row;
        uint2 v = make_uint2(0u, 0u);
        if (g < N_NODES) v = *(const uint2*)&x_bf16[g * D + c * 4];
        *(uint2*)&A_sh[row * A_STRIDE + c * 4] = v;
    }
    __syncthreads();

    // --- edge-parallel gather: 4 waves split the bucket's edge list
    int w    = tid >> 6;
    int lane = tid & 63;
    unsigned start = bucket_ptr[blockIdx.x];
    unsigned end   = bucket_ptr[blockIdx.x + 1];

    for (unsigned base = start + 64u * (unsigned)w; base < end; base += 256u) {
        unsigned idxe = base + (unsigned)lane;
        unsigned ent = (idxe < end) ? bucket_data[idxe] : DUMMY_ENT;
        atomicAdd(&deg[ent >> 16], 1u);        // one wave-wide deg update / 64 edges
        int enti = (int)ent;
        #pragma unroll
        for (int j = 0; j < 64; j += 4) {
            unsigned e0 = (unsigned)__shfl(enti, j + 0);
            unsigned e1 = (unsigned)__shfl(enti, j + 1);
            unsigned e2 = (unsigned)__shfl(enti, j + 2);
            unsigned e3 = (unsigned)__shfl(enti, j + 3);
            float v0 = bf2f(x_bf16[((e0 & 0xFFFFu) << 6) | lane]);
            float v1 = bf2f(x_bf16[((e1 & 0xFFFFu) << 6) | lane]);
            float v2 = bf2f(x_bf16[((e2 & 0xFFFFu) << 6) | lane]);
            float v3 = bf2f(x_bf16[((e3 & 0xFFFFu) << 6) | lane]);
            atomicAdd(&acc[((e0 >> 16) << 6) | lane], v0);
            atomicAdd(&acc[((e1 >> 16) << 6) | lane], v1);
            atomicAdd(&acc[((e2 >> 16) << 6) | lane], v2);
            atomicAdd(&acc[((e3 >> 16) << 6) | lane], v3);
        }
    }
    __syncthreads();

    // --- mean -> bf16 into A_sh (k>=64)
    for (int idx = tid; idx < 64 * 16; idx += 256) {
        int row = idx >> 4;
        int c   = idx & 15;
        unsigned dg = deg[row];
        float inv = dg ? 1.0f / (float)dg : 0.0f;
        const float* ap = &acc[row * 64 + c * 4];
        uint2 p;
        p.x = pack2(ap[0] * inv, ap[1] * inv);
        p.y = pack2(ap[2] * inv, ap[3] * inv);
        *(uint2*)&A_sh[row * A_STRIDE + 64 + c * 4] = p;
    }
    __syncthreads();

    // --- stage B (overwrites acc region)
    for (int idx = tid; idx < 64 * 32; idx += 256) {
        int n = idx >> 5;
        int c = idx & 31;
        uint2 v = *(const uint2*)&B_packed[n * 128 + c * 4];
        *(uint2*)&ubuf[n * A_STRIDE + c * 4] = v;
    }
    __syncthreads();

    // --- MFMA (layout verified rounds 2/4)
    int quad = lane >> 4;
    int l15  = lane & 15;

    f32x4 accr[4] = {{0.f,0.f,0.f,0.f},{0.f,0.f,0.f,0.f},{0.f,0.f,0.f,0.f},{0.f,0.f,0.f,0.f}};

    #pragma unroll
    for (int k0 = 0; k0 < 128; k0 += 32) {
        short8 a = *(const short8*)&A_sh[(16 * w + l15) * A_STRIDE + k0 + quad * 8];
        #pragma unroll
        for (int nt = 0; nt < 4; ++nt) {
            short8 b = *(const short8*)&ubuf[(16 * nt + l15) * A_STRIDE + k0 + quad * 8];
            accr[nt] = __builtin_amdgcn_mfma_f32_16x16x32_bf16(a, b, accr[nt], 0, 0, 0);
        }
    }

    #pragma unroll
    for (int nt = 0; nt < 4; ++nt) {
        int col = nt * 16 + l15;
        float bs = b_self[col];
        float bm = b_msg[col];
        #pragma unroll
        for (int r = 0; r < 4; ++r) {
            int lrow = 16 * w + quad * 4 + r;
            int grow = r0 + lrow;
            if (grow < N_NODES) {
                float v = accr[nt][r] + bs + (deg[lrow] > 0u ? bm : 0.0f);
                out[grow * D + col] = v;
            }
        }
    }
}

// ---------------------------------------------------------------------------
extern "C" void kernel_launch(void* const* d_in, const int* in_sizes, int n_in,
                              void* d_out, int out_size, void* d_ws, size_t ws_size,
                              hipStream_t stream) {
    const float* x      = (const float*)d_in[0];
    const int*   edges  = (const int*)  d_in[1];
    const float* W_msg  = (const float*)d_in[2];
    const float* b_msg  = (const float*)d_in[3];
    const float* W_self = (const float*)d_in[4];
    const float* b_self = (const float*)d_in[5];
    float*       out    = (float*)d_out;

    // workspace layout (bytes), total ~9.6 MB
    char* ws = (char*)d_ws;
    unsigned*       counts      = (unsigned*)(ws + 0);         // NB u32
    unsigned*       bucket_ptr  = (unsigned*)(ws + 4096);      // NB+1 u32
    unsigned*       cursor      = (unsigned*)(ws + 8192);      // NB u32
    unsigned short* B_packed    = (unsigned short*)(ws + 12288);   // 16 KB
    unsigned*       bucket_data = (unsigned*)(ws + 28672);     // 3.2 MB
    unsigned short* x_bf16      = (unsigned short*)(ws + 3228672); // 6.4 MB

    hipMemsetAsync(counts, 0, NB * sizeof(unsigned), stream);

    k_prep<<<256, 256, 0, stream>>>(x, x_bf16, edges, counts);
    k_scan<<<1, 1024, 0, stream>>>(counts, bucket_ptr, cursor, W_msg, W_self, B_packed);
    k_bin_place<<<256, 256, 0, stream>>>(edges, cursor, bucket_data);
    k_fused<<<NB, 256, 0, stream>>>(x_bf16, B_packed, b_msg, b_self,
                                    bucket_ptr, bucket_data, out);
}

// Round 6
// 212.685 us; speedup vs baseline: 2.2616x; 2.2616x over previous
//
#include <hip/hip_runtime.h>

constexpr int N_NODES = 50000;
constexpr int N_EDGES = 800000;
constexpr int D = 64;
constexpr int NB = (N_NODES + 63) / 64;      // 782 buckets of 64 dst nodes

typedef __attribute__((ext_vector_type(8))) short short8;
typedef __attribute__((ext_vector_type(4))) float f32x4;

static __device__ inline unsigned short f2bf(float f) {
    unsigned u = __float_as_uint(f);
    unsigned r = (u + 0x7FFFu + ((u >> 16) & 1u)) >> 16;   // RNE
    return (unsigned short)r;
}
static __device__ inline unsigned pack2(float lo, float hi) {
    return (unsigned)f2bf(lo) | ((unsigned)f2bf(hi) << 16);
}
static __device__ inline float bf2f(unsigned short b) {
    return __uint_as_float((unsigned)b << 16);
}

constexpr unsigned DUMMY_ENT = 64u << 16;    // d=64 (sink row), src=0
constexpr float FIX_SCALE    = 65536.0f;
constexpr float FIX_INV      = 1.0f / 65536.0f;

// ---------------------------------------------------------------------------
// 1) prep: x fp32 -> bf16 (grid-stride) + bucket histogram (LDS -> global)
// ---------------------------------------------------------------------------
__global__ __launch_bounds__(256) void k_prep(
    const float* __restrict__ x, unsigned short* __restrict__ xb,
    const int* __restrict__ edge_index, unsigned* __restrict__ g_counts)
{
    __shared__ unsigned h[NB];
    int tid = threadIdx.x;
    for (int b = tid; b < NB; b += 256) h[b] = 0u;

    int gid = blockIdx.x * 256 + tid;
    for (int t = gid; t < N_NODES * D / 4; t += 65536) {
        float4 v = ((const float4*)x)[t];
        uint2 p;
        p.x = pack2(v.x, v.y);
        p.y = pack2(v.z, v.w);
        ((uint2*)xb)[t] = p;
    }
    __syncthreads();
    for (int t = gid; t < N_EDGES; t += 65536) {
        int col = edge_index[N_EDGES + t];
        atomicAdd(&h[col >> 6], 1u);
    }
    __syncthreads();
    for (int b = tid; b < NB; b += 256) {
        unsigned c = h[b];
        if (c) atomicAdd(&g_counts[b], c);
    }
}

// ---------------------------------------------------------------------------
// 2) scan 782 bucket counts -> bucket_ptr + cursor; pack W -> bf16 B_packed
// ---------------------------------------------------------------------------
__global__ __launch_bounds__(1024) void k_scan(
    const unsigned* __restrict__ counts,
    unsigned* __restrict__ bucket_ptr, unsigned* __restrict__ cursor,
    const float* __restrict__ W_msg, const float* __restrict__ W_self,
    unsigned short* __restrict__ B_packed)
{
    __shared__ unsigned s[1024];
    int t = threadIdx.x;
    unsigned c = (t < NB) ? counts[t] : 0u;
    s[t] = c;
    __syncthreads();
    for (int off = 1; off < 1024; off <<= 1) {
        unsigned v = (t >= off) ? s[t - off] : 0u;
        __syncthreads();
        s[t] += v;
        __syncthreads();
    }
    if (t < NB) {
        unsigned e = s[t] - c;     // exclusive
        bucket_ptr[t] = e;
        cursor[t] = e;
    }
    if (t == 0) bucket_ptr[NB] = (unsigned)N_EDGES;

    for (int idx = t; idx < 64 * 128; idx += 1024) {
        int n = idx >> 7;
        int k = idx & 127;
        float v = (k < 64) ? W_self[n * 64 + k] : W_msg[n * 64 + (k - 64)];
        B_packed[idx] = f2bf(v);
    }
}

// ---------------------------------------------------------------------------
// 3) two-pass binning, 64 fat blocks (12500 edges each) so per-bucket runs
//    are ~16 contiguous entries (full 64B lines -> low write amplification).
// ---------------------------------------------------------------------------
constexpr int BIN_BLOCKS = 64;
constexpr int EDGES_PER_BIN_BLOCK = (N_EDGES + BIN_BLOCKS - 1) / BIN_BLOCKS;  // 12500

__global__ __launch_bounds__(256) void k_bin_place(
    const int* __restrict__ edge_index,
    unsigned* __restrict__ g_cursor, unsigned* __restrict__ bucket_data)
{
    __shared__ unsigned lcount[NB];
    __shared__ unsigned lbase[NB];

    int tid = threadIdx.x;
    int e0 = blockIdx.x * EDGES_PER_BIN_BLOCK;
    int e1 = min(e0 + EDGES_PER_BIN_BLOCK, N_EDGES);

    for (int b = tid; b < NB; b += 256) lcount[b] = 0u;
    __syncthreads();

    for (int e = e0 + tid; e < e1; e += 256)
        atomicAdd(&lcount[edge_index[N_EDGES + e] >> 6], 1u);
    __syncthreads();

    for (int b = tid; b < NB; b += 256) {
        unsigned c = lcount[b];
        lbase[b] = c ? atomicAdd(&g_cursor[b], c) : 0u;
    }
    __syncthreads();
    for (int b = tid; b < NB; b += 256) lcount[b] = 0u;
    __syncthreads();

    for (int e = e0 + tid; e < e1; e += 256) {
        int dst = edge_index[N_EDGES + e];
        int src = edge_index[e];
        int b = dst >> 6;
        unsigned off = atomicAdd(&lcount[b], 1u);
        bucket_data[lbase[b] + off] = (unsigned)src | ((unsigned)(dst & 63) << 16);
    }
}

// ---------------------------------------------------------------------------
// 4) fused: edge-parallel gather via i32 fixed-point ds_add_u32 (native,
//    no CAS) + scalar-broadcast entries (readlane) + bf16 MFMA GEMM.
// ---------------------------------------------------------------------------
constexpr int A_STRIDE = 136;   // u16 units; 272B row stride

__global__ __launch_bounds__(256) void k_fused(
    const unsigned short* __restrict__ x_bf16,
    const unsigned short* __restrict__ B_packed,
    const float* __restrict__ b_msg, const float* __restrict__ b_self,
    const unsigned* __restrict__ bucket_ptr,
    const unsigned* __restrict__ bucket_data,
    float* __restrict__ out)
{
    __shared__ __align__(16) unsigned short A_sh[64 * A_STRIDE];
    __shared__ __align__(16) unsigned short ubuf[64 * A_STRIDE];  // acc / B_sh union
    __shared__ unsigned deg[64];

    unsigned* acci = (unsigned*)ubuf;   // 65*64 u32 = 16640 B <= 17408 B

    int tid = threadIdx.x;
    int r0 = blockIdx.x * 64;

    // zero acc (65 rows: 64 real + sink) + deg; stage x rows into A_sh (k<64)
    for (int i = tid; i < 65 * 64; i += 256) acci[i] = 0u;
    if (tid < 64) deg[tid] = 0u;
    for (int idx = tid; idx < 64 * 16; idx += 256) {
        int row = idx >> 4;
        int c   = idx & 15;
        int g   = r0 + row;
        uint2 v = make_uint2(0u, 0u);
        if (g < N_NODES) v = *(const uint2*)&x_bf16[g * D + c * 4];
        *(uint2*)&A_sh[row * A_STRIDE + c * 4] = v;
    }
    __syncthreads();

    // --- edge-parallel gather: 4 waves split the bucket's edge list.
    int w    = tid >> 6;
    int lane = tid & 63;
    unsigned start = bucket_ptr[blockIdx.x];
    unsigned end   = bucket_ptr[blockIdx.x + 1];

    int my_deg = 0;   // per-lane: #edges with dst-low == lane

    for (unsigned base = start + 64u * (unsigned)w; base < end; base += 256u) {
        unsigned idxe = base + (unsigned)lane;
        unsigned entv = (idxe < end) ? bucket_data[idxe] : DUMMY_ENT;
        int enti = (int)entv;
        #pragma unroll
        for (int j = 0; j < 64; ++j) {
            unsigned e   = (unsigned)__builtin_amdgcn_readlane(enti, j);  // SGPR
            unsigned src = e & 0xFFFFu;
            unsigned d   = e >> 16;          // 0..63, or 64 = sink
            float v = bf2f(x_bf16[(src << 6) + (unsigned)lane]);
            int  vi = (int)(v * FIX_SCALE);  // trunc; err <= 2^-16/edge
            atomicAdd(&acci[(d << 6) + (unsigned)lane], (unsigned)vi);
            my_deg += ((unsigned)lane == d) ? 1 : 0;
        }
    }
    atomicAdd(&deg[lane], (unsigned)my_deg);   // 4 wave-wide ops total
    __syncthreads();

    // --- mean -> bf16 into A_sh (k>=64)
    for (int idx = tid; idx < 64 * 16; idx += 256) {
        int row = idx >> 4;
        int c   = idx & 15;
        unsigned dg = deg[row];
        float inv = dg ? (FIX_INV / (float)dg) : 0.0f;
        const int* ap = (const int*)&acci[row * 64 + c * 4];
        uint2 p;
        p.x = pack2((float)ap[0] * inv, (float)ap[1] * inv);
        p.y = pack2((float)ap[2] * inv, (float)ap[3] * inv);
        *(uint2*)&A_sh[row * A_STRIDE + 64 + c * 4] = p;
    }
    __syncthreads();

    // --- stage B (overwrites acc region)
    for (int idx = tid; idx < 64 * 32; idx += 256) {
        int n = idx >> 5;
        int c = idx & 31;
        uint2 v = *(const uint2*)&B_packed[n * 128 + c * 4];
        *(uint2*)&ubuf[n * A_STRIDE + c * 4] = v;
    }
    __syncthreads();

    // --- MFMA (layout verified rounds 2/4/5)
    int quad = lane >> 4;
    int l15  = lane & 15;

    f32x4 accr[4] = {{0.f,0.f,0.f,0.f},{0.f,0.f,0.f,0.f},{0.f,0.f,0.f,0.f},{0.f,0.f,0.f,0.f}};

    #pragma unroll
    for (int k0 = 0; k0 < 128; k0 += 32) {
        short8 a = *(const short8*)&A_sh[(16 * w + l15) * A_STRIDE + k0 + quad * 8];
        #pragma unroll
        for (int nt = 0; nt < 4; ++nt) {
            short8 b = *(const short8*)&ubuf[(16 * nt + l15) * A_STRIDE + k0 + quad * 8];
            accr[nt] = __builtin_amdgcn_mfma_f32_16x16x32_bf16(a, b, accr[nt], 0, 0, 0);
        }
    }

    #pragma unroll
    for (int nt = 0; nt < 4; ++nt) {
        int col = nt * 16 + l15;
        float bs = b_self[col];
        float bm = b_msg[col];
        #pragma unroll
        for (int r = 0; r < 4; ++r) {
            int lrow = 16 * w + quad * 4 + r;
            int grow = r0 + lrow;
            if (grow < N_NODES) {
                float v = accr[nt][r] + bs + (deg[lrow] > 0u ? bm : 0.0f);
                out[grow * D + col] = v;
            }
        }
    }
}

// ---------------------------------------------------------------------------
extern "C" void kernel_launch(void* const* d_in, const int* in_sizes, int n_in,
                              void* d_out, int out_size, void* d_ws, size_t ws_size,
                              hipStream_t stream) {
    const float* x      = (const float*)d_in[0];
    const int*   edges  = (const int*)  d_in[1];
    const float* W_msg  = (const float*)d_in[2];
    const float* b_msg  = (const float*)d_in[3];
    const float* W_self = (const float*)d_in[4];
    const float* b_self = (const float*)d_in[5];
    float*       out    = (float*)d_out;

    // workspace layout (bytes), total ~9.6 MB
    char* ws = (char*)d_ws;
    unsigned*       counts      = (unsigned*)(ws + 0);         // NB u32
    unsigned*       bucket_ptr  = (unsigned*)(ws + 4096);      // NB+1 u32
    unsigned*       cursor      = (unsigned*)(ws + 8192);      // NB u32
    unsigned short* B_packed    = (unsigned short*)(ws + 12288);   // 16 KB
    unsigned*       bucket_data = (unsigned*)(ws + 28672);     // 3.2 MB
    unsigned short* x_bf16      = (unsigned short*)(ws + 3228672); // 6.4 MB

    hipMemsetAsync(counts, 0, NB * sizeof(unsigned), stream);

    k_prep<<<256, 256, 0, stream>>>(x, x_bf16, edges, counts);
    k_scan<<<1, 1024, 0, stream>>>(counts, bucket_ptr, cursor, W_msg, W_self, B_packed);
    k_bin_place<<<BIN_BLOCKS, 256, 0, stream>>>(edges, cursor, bucket_data);
    k_fused<<<NB, 256, 0, stream>>>(x_bf16, B_packed, b_msg, b_self,
                                    bucket_ptr, bucket_data, out);
}

// Round 7
// 139.232 us; speedup vs baseline: 3.4548x; 1.5276x over previous
//
#include <hip/hip_runtime.h>

constexpr int N_NODES = 50000;
constexpr int N_EDGES = 800000;
constexpr int D = 64;
constexpr int NB = (N_NODES + 63) / 64;      // 782 buckets of 64 dst nodes

typedef __attribute__((ext_vector_type(8))) short short8;
typedef __attribute__((ext_vector_type(4))) float f32x4;

static __device__ inline unsigned short f2bf(float f) {
    unsigned u = __float_as_uint(f);
    unsigned r = (u + 0x7FFFu + ((u >> 16) & 1u)) >> 16;   // RNE
    return (unsigned short)r;
}
static __device__ inline unsigned pack2(float lo, float hi) {
    return (unsigned)f2bf(lo) | ((unsigned)f2bf(hi) << 16);
}
static __device__ inline float bf2f(unsigned short b) {
    return __uint_as_float((unsigned)b << 16);
}

constexpr unsigned DUMMY_ENT = 64u << 16;    // d=64 (sink row), src=0
constexpr float FIX_SCALE    = 65536.0f;
constexpr float FIX_INV      = 1.0f / 65536.0f;

// ---------------------------------------------------------------------------
// 1) prep: x fp32 -> bf16 (grid-stride) + bucket histogram (LDS -> global)
// ---------------------------------------------------------------------------
__global__ __launch_bounds__(256) void k_prep(
    const float* __restrict__ x, unsigned short* __restrict__ xb,
    const int* __restrict__ edge_index, unsigned* __restrict__ g_counts)
{
    __shared__ unsigned h[NB];
    int tid = threadIdx.x;
    for (int b = tid; b < NB; b += 256) h[b] = 0u;

    int gid = blockIdx.x * 256 + tid;
    for (int t = gid; t < N_NODES * D / 4; t += 65536) {
        float4 v = ((const float4*)x)[t];
        uint2 p;
        p.x = pack2(v.x, v.y);
        p.y = pack2(v.z, v.w);
        ((uint2*)xb)[t] = p;
    }
    __syncthreads();
    for (int t = gid; t < N_EDGES; t += 65536) {
        int col = edge_index[N_EDGES + t];
        atomicAdd(&h[col >> 6], 1u);
    }
    __syncthreads();
    for (int b = tid; b < NB; b += 256) {
        unsigned c = h[b];
        if (c) atomicAdd(&g_counts[b], c);
    }
}

// ---------------------------------------------------------------------------
// 2) scan 782 bucket counts -> bucket_ptr + cursor; pack W -> bf16 B_packed
// ---------------------------------------------------------------------------
__global__ __launch_bounds__(1024) void k_scan(
    const unsigned* __restrict__ counts,
    unsigned* __restrict__ bucket_ptr, unsigned* __restrict__ cursor,
    const float* __restrict__ W_msg, const float* __restrict__ W_self,
    unsigned short* __restrict__ B_packed)
{
    __shared__ unsigned s[1024];
    int t = threadIdx.x;
    unsigned c = (t < NB) ? counts[t] : 0u;
    s[t] = c;
    __syncthreads();
    for (int off = 1; off < 1024; off <<= 1) {
        unsigned v = (t >= off) ? s[t - off] : 0u;
        __syncthreads();
        s[t] += v;
        __syncthreads();
    }
    if (t < NB) {
        unsigned e = s[t] - c;     // exclusive
        bucket_ptr[t] = e;
        cursor[t] = e;
    }
    if (t == 0) bucket_ptr[NB] = (unsigned)N_EDGES;

    for (int idx = t; idx < 64 * 128; idx += 1024) {
        int n = idx >> 7;
        int k = idx & 127;
        float v = (k < 64) ? W_self[n * 64 + k] : W_msg[n * 64 + (k - 64)];
        B_packed[idx] = f2bf(v);
    }
}

// ---------------------------------------------------------------------------
// 3) two-pass binning: 128 blocks x 512 threads (6250 edges each; ~8-entry
//    bucket runs keep write amplification ~2x while using half the CUs).
// ---------------------------------------------------------------------------
constexpr int BIN_BLOCKS = 128;
constexpr int EDGES_PER_BIN_BLOCK = (N_EDGES + BIN_BLOCKS - 1) / BIN_BLOCKS;  // 6250

__global__ __launch_bounds__(512) void k_bin_place(
    const int* __restrict__ edge_index,
    unsigned* __restrict__ g_cursor, unsigned* __restrict__ bucket_data)
{
    __shared__ unsigned lcount[NB];
    __shared__ unsigned lbase[NB];

    int tid = threadIdx.x;
    int e0 = blockIdx.x * EDGES_PER_BIN_BLOCK;
    int e1 = min(e0 + EDGES_PER_BIN_BLOCK, N_EDGES);

    for (int b = tid; b < NB; b += 512) lcount[b] = 0u;
    __syncthreads();

    for (int e = e0 + tid; e < e1; e += 512)
        atomicAdd(&lcount[edge_index[N_EDGES + e] >> 6], 1u);
    __syncthreads();

    for (int b = tid; b < NB; b += 512) {
        unsigned c = lcount[b];
        lbase[b] = c ? atomicAdd(&g_cursor[b], c) : 0u;
    }
    __syncthreads();
    for (int b = tid; b < NB; b += 512) lcount[b] = 0u;
    __syncthreads();

    for (int e = e0 + tid; e < e1; e += 512) {
        int dst = edge_index[N_EDGES + e];
        int src = edge_index[e];
        int b = dst >> 6;
        unsigned off = atomicAdd(&lcount[b], 1u);
        bucket_data[lbase[b] + off] = (unsigned)src | ((unsigned)(dst & 63) << 16);
    }
}

// ---------------------------------------------------------------------------
// 4) fused: 512 threads (8 waves). Gather with explicit MLP=8 load batches +
//    i32 fixed-point ds_add; MFMA with 8 waves x 2 n-tiles.
// ---------------------------------------------------------------------------
constexpr int A_STRIDE = 136;   // u16 units; 272B row stride

__global__ __launch_bounds__(512) void k_fused(
    const unsigned short* __restrict__ x_bf16,
    const unsigned short* __restrict__ B_packed,
    const float* __restrict__ b_msg, const float* __restrict__ b_self,
    const unsigned* __restrict__ bucket_ptr,
    const unsigned* __restrict__ bucket_data,
    float* __restrict__ out)
{
    __shared__ __align__(16) unsigned short A_sh[64 * A_STRIDE];
    __shared__ __align__(16) unsigned short ubuf[64 * A_STRIDE];  // acc / B_sh union
    __shared__ unsigned deg[64];

    unsigned* acci = (unsigned*)ubuf;   // 65*64 u32 = 16640 B <= 17408 B

    int tid = threadIdx.x;
    int r0 = blockIdx.x * 64;

    for (int i = tid; i < 65 * 64; i += 512) acci[i] = 0u;
    if (tid < 64) deg[tid] = 0u;
    for (int idx = tid; idx < 64 * 16; idx += 512) {
        int row = idx >> 4;
        int c   = idx & 15;
        int g   = r0 + row;
        uint2 v = make_uint2(0u, 0u);
        if (g < N_NODES) v = *(const uint2*)&x_bf16[g * D + c * 4];
        *(uint2*)&A_sh[row * A_STRIDE + c * 4] = v;
    }
    __syncthreads();

    // --- edge-parallel gather: 8 waves split the bucket's edge list.
    int w    = tid >> 6;       // 0..7
    int lane = tid & 63;
    unsigned start = bucket_ptr[blockIdx.x];
    unsigned end   = bucket_ptr[blockIdx.x + 1];

    int my_deg = 0;

    for (unsigned base = start + 64u * (unsigned)w; base < end; base += 512u) {
        unsigned idxe = base + (unsigned)lane;
        unsigned entv = (idxe < end) ? bucket_data[idxe] : DUMMY_ENT;
        int enti = (int)entv;
        #pragma unroll
        for (int j0 = 0; j0 < 64; j0 += 8) {
            float    v[8];
            unsigned dd[8];
            #pragma unroll
            for (int jj = 0; jj < 8; ++jj) {              // 8 loads in flight
                unsigned e = (unsigned)__builtin_amdgcn_readlane(enti, j0 + jj);
                dd[jj] = e >> 16;
                v[jj]  = bf2f(x_bf16[((e & 0xFFFFu) << 6) + (unsigned)lane]);
            }
            #pragma unroll
            for (int jj = 0; jj < 8; ++jj) {
                int vi = (int)(v[jj] * FIX_SCALE);
                atomicAdd(&acci[(dd[jj] << 6) + (unsigned)lane], (unsigned)vi);
                my_deg += ((unsigned)lane == dd[jj]) ? 1 : 0;
            }
        }
    }
    atomicAdd(&deg[lane], (unsigned)my_deg);
    __syncthreads();

    // --- mean -> bf16 into A_sh (k>=64)
    for (int idx = tid; idx < 64 * 16; idx += 512) {
        int row = idx >> 4;
        int c   = idx & 15;
        unsigned dg = deg[row];
        float inv = dg ? (FIX_INV / (float)dg) : 0.0f;
        const int* ap = (const int*)&acci[row * 64 + c * 4];
        uint2 p;
        p.x = pack2((float)ap[0] * inv, (float)ap[1] * inv);
        p.y = pack2((float)ap[2] * inv, (float)ap[3] * inv);
        *(uint2*)&A_sh[row * A_STRIDE + 64 + c * 4] = p;
    }
    __syncthreads();

    // --- stage B (overwrites acc region)
    for (int idx = tid; idx < 64 * 32; idx += 512) {
        int n = idx >> 5;
        int c = idx & 31;
        uint2 v = *(const uint2*)&B_packed[n * 128 + c * 4];
        *(uint2*)&ubuf[n * A_STRIDE + c * 4] = v;
    }
    __syncthreads();

    // --- MFMA: wave w -> m-rows 16*(w&3), n-tiles {2*(w>>2), 2*(w>>2)+1}
    int wm   = w & 3;
    int ng   = (w >> 2) * 2;
    int quad = lane >> 4;
    int l15  = lane & 15;

    f32x4 accr[2] = {{0.f,0.f,0.f,0.f},{0.f,0.f,0.f,0.f}};

    #pragma unroll
    for (int k0 = 0; k0 < 128; k0 += 32) {
        short8 a = *(const short8*)&A_sh[(16 * wm + l15) * A_STRIDE + k0 + quad * 8];
        #pragma unroll
        for (int t = 0; t < 2; ++t) {
            short8 b = *(const short8*)&ubuf[(16 * (ng + t) + l15) * A_STRIDE + k0 + quad * 8];
            accr[t] = __builtin_amdgcn_mfma_f32_16x16x32_bf16(a, b, accr[t], 0, 0, 0);
        }
    }

    #pragma unroll
    for (int t = 0; t < 2; ++t) {
        int col = (ng + t) * 16 + l15;
        float bs = b_self[col];
        float bm = b_msg[col];
        #pragma unroll
        for (int r = 0; r < 4; ++r) {
            int lrow = 16 * wm + quad * 4 + r;
            int grow = r0 + lrow;
            if (grow < N_NODES) {
                float vv = accr[t][r] + bs + (deg[lrow] > 0u ? bm : 0.0f);
                out[grow * D + col] = vv;
            }
        }
    }
}

// ---------------------------------------------------------------------------
extern "C" void kernel_launch(void* const* d_in, const int* in_sizes, int n_in,
                              void* d_out, int out_size, void* d_ws, size_t ws_size,
                              hipStream_t stream) {
    const float* x      = (const float*)d_in[0];
    const int*   edges  = (const int*)  d_in[1];
    const float* W_msg  = (const float*)d_in[2];
    const float* b_msg  = (const float*)d_in[3];
    const float* W_self = (const float*)d_in[4];
    const float* b_self = (const float*)d_in[5];
    float*       out    = (float*)d_out;

    // workspace layout (bytes), total ~9.6 MB
    char* ws = (char*)d_ws;
    unsigned*       counts      = (unsigned*)(ws + 0);         // NB u32
    unsigned*       bucket_ptr  = (unsigned*)(ws + 4096);      // NB+1 u32
    unsigned*       cursor      = (unsigned*)(ws + 8192);      // NB u32
    unsigned short* B_packed    = (unsigned short*)(ws + 12288);   // 16 KB
    unsigned*       bucket_data = (unsigned*)(ws + 28672);     // 3.2 MB
    unsigned short* x_bf16      = (unsigned short*)(ws + 3228672); // 6.4 MB

    hipMemsetAsync(counts, 0, NB * sizeof(unsigned), stream);

    k_prep<<<256, 256, 0, stream>>>(x, x_bf16, edges, counts);
    k_scan<<<1, 1024, 0, stream>>>(counts, bucket_ptr, cursor, W_msg, W_self, B_packed);
    k_bin_place<<<BIN_BLOCKS, 512, 0, stream>>>(edges, cursor, bucket_data);
    k_fused<<<NB, 512, 0, stream>>>(x_bf16, B_packed, b_msg, b_self,
                                    bucket_ptr, bucket_data, out);
}

// Round 8
// 125.261 us; speedup vs baseline: 3.8401x; 1.1115x over previous
//
#include <hip/hip_runtime.h>

constexpr int N_NODES = 50000;
constexpr int N_EDGES = 800000;
constexpr int D = 64;
constexpr int NB = (N_NODES + 63) / 64;      // 782 buckets of 64 dst nodes
constexpr int BUCKET_CAP = 1280;             // mean load 1023, sigma 32 -> 8-sigma pad

typedef __attribute__((ext_vector_type(8))) short short8;
typedef __attribute__((ext_vector_type(4))) float f32x4;

static __device__ inline unsigned short f2bf(float f) {
    unsigned u = __float_as_uint(f);
    unsigned r = (u + 0x7FFFu + ((u >> 16) & 1u)) >> 16;   // RNE
    return (unsigned short)r;
}
static __device__ inline unsigned pack2(float lo, float hi) {
    return (unsigned)f2bf(lo) | ((unsigned)f2bf(hi) << 16);
}
static __device__ inline float bf2f(unsigned short b) {
    return __uint_as_float((unsigned)b << 16);
}

constexpr unsigned DUMMY_ENT = 64u << 16;    // d=64 (sink row), src=0
constexpr float FIX_SCALE    = 65536.0f;
constexpr float FIX_INV      = 1.0f / 65536.0f;

// ---------------------------------------------------------------------------
// 1) prep: x fp32 -> bf16; block 0 packs W to bf16; block 1 inits cursors.
//    (no histogram / scan / memset needed with padded buckets)
// ---------------------------------------------------------------------------
__global__ __launch_bounds__(256) void k_prep(
    const float* __restrict__ x, unsigned short* __restrict__ xb,
    const float* __restrict__ W_msg, const float* __restrict__ W_self,
    unsigned short* __restrict__ B_packed, unsigned* __restrict__ cursor)
{
    int tid = threadIdx.x;
    int gid = blockIdx.x * 256 + tid;

    for (int t = gid; t < N_NODES * D / 4; t += 512 * 256) {
        float4 v = ((const float4*)x)[t];
        uint2 p;
        p.x = pack2(v.x, v.y);
        p.y = pack2(v.z, v.w);
        ((uint2*)xb)[t] = p;
    }
    if (blockIdx.x == 0) {
        for (int idx = tid; idx < 64 * 128; idx += 256) {
            int n = idx >> 7;
            int k = idx & 127;
            float v = (k < 64) ? W_self[n * 64 + k] : W_msg[n * 64 + (k - 64)];
            B_packed[idx] = f2bf(v);
        }
    } else if (blockIdx.x == 1) {
        for (int b = tid; b < NB; b += 256)
            cursor[b] = (unsigned)b * BUCKET_CAP;
    }
}

// ---------------------------------------------------------------------------
// 2) two-pass binning into padded buckets: LDS count -> one cursor atomic per
//    (block,bucket) -> contiguous writes. 128 fat blocks keep runs ~8 long.
// ---------------------------------------------------------------------------
constexpr int BIN_BLOCKS = 128;
constexpr int EDGES_PER_BIN_BLOCK = (N_EDGES + BIN_BLOCKS - 1) / BIN_BLOCKS;  // 6250

__global__ __launch_bounds__(512) void k_bin_place(
    const int* __restrict__ edge_index,
    unsigned* __restrict__ g_cursor, unsigned* __restrict__ bucket_data)
{
    __shared__ unsigned lcount[NB];
    __shared__ unsigned lbase[NB];

    int tid = threadIdx.x;
    int e0 = blockIdx.x * EDGES_PER_BIN_BLOCK;
    int e1 = min(e0 + EDGES_PER_BIN_BLOCK, N_EDGES);

    for (int b = tid; b < NB; b += 512) lcount[b] = 0u;
    __syncthreads();

    for (int e = e0 + tid; e < e1; e += 512)
        atomicAdd(&lcount[edge_index[N_EDGES + e] >> 6], 1u);
    __syncthreads();

    for (int b = tid; b < NB; b += 512) {
        unsigned c = lcount[b];
        lbase[b] = c ? atomicAdd(&g_cursor[b], c) : 0u;
    }
    __syncthreads();
    for (int b = tid; b < NB; b += 512) lcount[b] = 0u;
    __syncthreads();

    for (int e = e0 + tid; e < e1; e += 512) {
        int dst = edge_index[N_EDGES + e];
        int src = edge_index[e];
        int b = dst >> 6;
        unsigned off = atomicAdd(&lcount[b], 1u);
        bucket_data[lbase[b] + off] = (unsigned)src | ((unsigned)(dst & 63) << 16);
    }
}

// ---------------------------------------------------------------------------
// 3) fused: 512 threads (8 waves). Gather with MLP=8 load batches +
//    i32 fixed-point ds_add; MFMA with 8 waves x 2 n-tiles.
// ---------------------------------------------------------------------------
constexpr int A_STRIDE = 136;   // u16 units; 272B row stride

__global__ __launch_bounds__(512) void k_fused(
    const unsigned short* __restrict__ x_bf16,
    const unsigned short* __restrict__ B_packed,
    const float* __restrict__ b_msg, const float* __restrict__ b_self,
    const unsigned* __restrict__ cursor,
    const unsigned* __restrict__ bucket_data,
    float* __restrict__ out)
{
    __shared__ __align__(16) unsigned short A_sh[64 * A_STRIDE];
    __shared__ __align__(16) unsigned short ubuf[64 * A_STRIDE];  // acc / B_sh union
    __shared__ unsigned deg[64];

    unsigned* acci = (unsigned*)ubuf;   // 65*64 u32 = 16640 B <= 17408 B

    int tid = threadIdx.x;
    int r0 = blockIdx.x * 64;

    for (int i = tid; i < 65 * 64; i += 512) acci[i] = 0u;
    if (tid < 64) deg[tid] = 0u;
    for (int idx = tid; idx < 64 * 16; idx += 512) {
        int row = idx >> 4;
        int c   = idx & 15;
        int g   = r0 + row;
        uint2 v = make_uint2(0u, 0u);
        if (g < N_NODES) v = *(const uint2*)&x_bf16[g * D + c * 4];
        *(uint2*)&A_sh[row * A_STRIDE + c * 4] = v;
    }
    __syncthreads();

    // --- edge-parallel gather: 8 waves split the bucket's edge list.
    int w    = tid >> 6;       // 0..7
    int lane = tid & 63;
    unsigned start = (unsigned)blockIdx.x * BUCKET_CAP;
    unsigned end   = cursor[blockIdx.x];          // final cursor = start + count

    int my_deg = 0;

    for (unsigned base = start + 64u * (unsigned)w; base < end; base += 512u) {
        unsigned idxe = base + (unsigned)lane;
        unsigned entv = (idxe < end) ? bucket_data[idxe] : DUMMY_ENT;
        int enti = (int)entv;
        #pragma unroll
        for (int j0 = 0; j0 < 64; j0 += 8) {
            float    v[8];
            unsigned dd[8];
            #pragma unroll
            for (int jj = 0; jj < 8; ++jj) {              // 8 loads in flight
                unsigned e = (unsigned)__builtin_amdgcn_readlane(enti, j0 + jj);
                dd[jj] = e >> 16;
                v[jj]  = bf2f(x_bf16[((e & 0xFFFFu) << 6) + (unsigned)lane]);
            }
            #pragma unroll
            for (int jj = 0; jj < 8; ++jj) {
                int vi = (int)(v[jj] * FIX_SCALE);
                atomicAdd(&acci[(dd[jj] << 6) + (unsigned)lane], (unsigned)vi);
                my_deg += ((unsigned)lane == dd[jj]) ? 1 : 0;
            }
        }
    }
    atomicAdd(&deg[lane], (unsigned)my_deg);
    __syncthreads();

    // --- mean -> bf16 into A_sh (k>=64)
    for (int idx = tid; idx < 64 * 16; idx += 512) {
        int row = idx >> 4;
        int c   = idx & 15;
        unsigned dg = deg[row];
        float inv = dg ? (FIX_INV / (float)dg) : 0.0f;
        const int* ap = (const int*)&acci[row * 64 + c * 4];
        uint2 p;
        p.x = pack2((float)ap[0] * inv, (float)ap[1] * inv);
        p.y = pack2((float)ap[2] * inv, (float)ap[3] * inv);
        *(uint2*)&A_sh[row * A_STRIDE + 64 + c * 4] = p;
    }
    __syncthreads();

    // --- stage B (overwrites acc region)
    for (int idx = tid; idx < 64 * 32; idx += 512) {
        int n = idx >> 5;
        int c = idx & 31;
        uint2 v = *(const uint2*)&B_packed[n * 128 + c * 4];
        *(uint2*)&ubuf[n * A_STRIDE + c * 4] = v;
    }
    __syncthreads();

    // --- MFMA: wave w -> m-rows 16*(w&3), n-tiles {2*(w>>2), 2*(w>>2)+1}
    int wm   = w & 3;
    int ng   = (w >> 2) * 2;
    int quad = lane >> 4;
    int l15  = lane & 15;

    f32x4 accr[2] = {{0.f,0.f,0.f,0.f},{0.f,0.f,0.f,0.f}};

    #pragma unroll
    for (int k0 = 0; k0 < 128; k0 += 32) {
        short8 a = *(const short8*)&A_sh[(16 * wm + l15) * A_STRIDE + k0 + quad * 8];
        #pragma unroll
        for (int t = 0; t < 2; ++t) {
            short8 b = *(const short8*)&ubuf[(16 * (ng + t) + l15) * A_STRIDE + k0 + quad * 8];
            accr[t] = __builtin_amdgcn_mfma_f32_16x16x32_bf16(a, b, accr[t], 0, 0, 0);
        }
    }

    #pragma unroll
    for (int t = 0; t < 2; ++t) {
        int col = (ng + t) * 16 + l15;
        float bs = b_self[col];
        float bm = b_msg[col];
        #pragma unroll
        for (int r = 0; r < 4; ++r) {
            int lrow = 16 * wm + quad * 4 + r;
            int grow = r0 + lrow;
            if (grow < N_NODES) {
                float vv = accr[t][r] + bs + (deg[lrow] > 0u ? bm : 0.0f);
                out[grow * D + col] = vv;
            }
        }
    }
}

// ---------------------------------------------------------------------------
extern "C" void kernel_launch(void* const* d_in, const int* in_sizes, int n_in,
                              void* d_out, int out_size, void* d_ws, size_t ws_size,
                              hipStream_t stream) {
    const float* x      = (const float*)d_in[0];
    const int*   edges  = (const int*)  d_in[1];
    const float* W_msg  = (const float*)d_in[2];
    const float* b_msg  = (const float*)d_in[3];
    const float* W_self = (const float*)d_in[4];
    const float* b_self = (const float*)d_in[5];
    float*       out    = (float*)d_out;

    // workspace layout (bytes), total ~10.5 MB
    char* ws = (char*)d_ws;
    unsigned*       cursor      = (unsigned*)(ws + 0);             // NB u32
    unsigned short* B_packed    = (unsigned short*)(ws + 4096);    // 16 KB
    unsigned*       bucket_data = (unsigned*)(ws + 20480);         // 782*1280*4 ~ 4 MB
    unsigned short* x_bf16      = (unsigned short*)(ws + 4030464); // 6.4 MB

    k_prep<<<512, 256, 0, stream>>>(x, x_bf16, W_msg, W_self, B_packed, cursor);
    k_bin_place<<<BIN_BLOCKS, 512, 0, stream>>>(edges, cursor, bucket_data);
    k_fused<<<NB, 512, 0, stream>>>(x_bf16, B_packed, b_msg, b_self,
                                    cursor, bucket_data, out);
}

// Round 9
// 123.376 us; speedup vs baseline: 3.8988x; 1.0153x over previous
//
#include <hip/hip_runtime.h>

constexpr int N_NODES = 50000;
constexpr int N_EDGES = 800000;
constexpr int D = 64;
constexpr int NB = (N_NODES + 63) / 64;      // 782 buckets of 64 dst nodes
constexpr int BUCKET_CAP = 1280;             // mean load 1023 -> 8-sigma pad

typedef __attribute__((ext_vector_type(8))) short short8;
typedef __attribute__((ext_vector_type(4))) float f32x4;

static __device__ inline unsigned short f2bf(float f) {
    unsigned u = __float_as_uint(f);
    unsigned r = (u + 0x7FFFu + ((u >> 16) & 1u)) >> 16;   // RNE
    return (unsigned short)r;
}
static __device__ inline unsigned pack2(float lo, float hi) {
    return (unsigned)f2bf(lo) | ((unsigned)f2bf(hi) << 16);
}
static __device__ inline float bf2f(unsigned short b) {
    return __uint_as_float((unsigned)b << 16);
}

// ---------------------------------------------------------------------------
// 1) prep: x fp32 -> bf16; block 0 packs W to bf16; block 1 inits cursors.
// ---------------------------------------------------------------------------
__global__ __launch_bounds__(256) void k_prep(
    const float* __restrict__ x, unsigned short* __restrict__ xb,
    const float* __restrict__ W_msg, const float* __restrict__ W_self,
    unsigned short* __restrict__ B_packed, unsigned* __restrict__ cursor)
{
    int tid = threadIdx.x;
    int gid = blockIdx.x * 256 + tid;

    for (int t = gid; t < N_NODES * D / 4; t += 512 * 256) {
        float4 v = ((const float4*)x)[t];
        uint2 p;
        p.x = pack2(v.x, v.y);
        p.y = pack2(v.z, v.w);
        ((uint2*)xb)[t] = p;
    }
    if (blockIdx.x == 0) {
        for (int idx = tid; idx < 64 * 128; idx += 256) {
            int n = idx >> 7;
            int k = idx & 127;
            float v = (k < 64) ? W_self[n * 64 + k] : W_msg[n * 64 + (k - 64)];
            B_packed[idx] = f2bf(v);
        }
    } else if (blockIdx.x == 1) {
        for (int b = tid; b < NB; b += 256)
            cursor[b] = (unsigned)b * BUCKET_CAP;
    }
}

// ---------------------------------------------------------------------------
// 2) two-pass binning into padded buckets (unchanged from round 8).
// ---------------------------------------------------------------------------
constexpr int BIN_BLOCKS = 128;
constexpr int EDGES_PER_BIN_BLOCK = (N_EDGES + BIN_BLOCKS - 1) / BIN_BLOCKS;  // 6250

__global__ __launch_bounds__(512) void k_bin_place(
    const int* __restrict__ edge_index,
    unsigned* __restrict__ g_cursor, unsigned* __restrict__ bucket_data)
{
    __shared__ unsigned lcount[NB];
    __shared__ unsigned lbase[NB];

    int tid = threadIdx.x;
    int e0 = blockIdx.x * EDGES_PER_BIN_BLOCK;
    int e1 = min(e0 + EDGES_PER_BIN_BLOCK, N_EDGES);

    for (int b = tid; b < NB; b += 512) lcount[b] = 0u;
    __syncthreads();

    for (int e = e0 + tid; e < e1; e += 512)
        atomicAdd(&lcount[edge_index[N_EDGES + e] >> 6], 1u);
    __syncthreads();

    for (int b = tid; b < NB; b += 512) {
        unsigned c = lcount[b];
        lbase[b] = c ? atomicAdd(&g_cursor[b], c) : 0u;
    }
    __syncthreads();
    for (int b = tid; b < NB; b += 512) lcount[b] = 0u;
    __syncthreads();

    for (int e = e0 + tid; e < e1; e += 512) {
        int dst = edge_index[N_EDGES + e];
        int src = edge_index[e];
        int b = dst >> 6;
        unsigned off = atomicAdd(&lcount[b], 1u);
        bucket_data[lbase[b] + off] = (unsigned)src | ((unsigned)(dst & 63) << 16);
    }
}

// ---------------------------------------------------------------------------
// 3) fused: LDS counting-sort by dst -> per-node sequential gather
//    (quarter-wave per edge, fp32 reg accumulation) -> bf16 MFMA GEMM.
// ---------------------------------------------------------------------------
constexpr int A_STRIDE = 136;   // u16 units; 272B row stride

__global__ __launch_bounds__(512) void k_fused(
    const unsigned short* __restrict__ x_bf16,
    const unsigned short* __restrict__ B_packed,
    const float* __restrict__ b_msg, const float* __restrict__ b_self,
    const unsigned* __restrict__ cursor,
    const unsigned* __restrict__ bucket_data,
    float* __restrict__ out)
{
    __shared__ __align__(16) unsigned short A_sh[64 * A_STRIDE];   // 17408 B
    __shared__ __align__(16) unsigned short B_sh[64 * A_STRIDE];   // 17408 B
    __shared__ unsigned short sorted_sh[BUCKET_CAP];               // 2560 B
    __shared__ unsigned cnt_sh[64];
    __shared__ unsigned off_sh[64];
    __shared__ unsigned woff_sh[64];

    int tid  = threadIdx.x;
    int w    = tid >> 6;       // wave 0..7
    int lane = tid & 63;
    int r0   = blockIdx.x * 64;

    unsigned start = (unsigned)blockIdx.x * BUCKET_CAP;
    unsigned end   = cursor[blockIdx.x];     // start + entry count

    // --- stage A (x rows, k<64) and B; zero counters
    if (tid < 64) cnt_sh[tid] = 0u;
    for (int idx = tid; idx < 64 * 16; idx += 512) {
        int row = idx >> 4;
        int c   = idx & 15;
        int g   = r0 + row;
        uint2 v = make_uint2(0u, 0u);
        if (g < N_NODES) v = *(const uint2*)&x_bf16[g * D + c * 4];
        *(uint2*)&A_sh[row * A_STRIDE + c * 4] = v;
    }
    for (int idx = tid; idx < 64 * 32; idx += 512) {
        int n = idx >> 5;
        int c = idx & 31;
        uint2 v = *(const uint2*)&B_packed[n * 128 + c * 4];
        *(uint2*)&B_sh[n * A_STRIDE + c * 4] = v;
    }
    __syncthreads();

    // --- counting sort by dst-low: count
    for (unsigned i = start + tid; i < end; i += 512u)
        atomicAdd(&cnt_sh[bucket_data[i] >> 16], 1u);
    __syncthreads();

    // scan (wave 0 only)
    if (tid < 64) {
        unsigned c = cnt_sh[tid];
        unsigned xsum = c;
        #pragma unroll
        for (int s = 1; s < 64; s <<= 1) {
            unsigned v = (unsigned)__shfl_up((int)xsum, s);
            if (lane >= s) xsum += v;
        }
        off_sh[tid]  = xsum - c;     // exclusive
        woff_sh[tid] = xsum - c;
    }
    __syncthreads();

    // scatter srcs into dst-ordered LDS list
    for (unsigned i = start + tid; i < end; i += 512u) {
        unsigned e = bucket_data[i];
        unsigned slot = atomicAdd(&woff_sh[e >> 16], 1u);
        sorted_sh[slot] = (unsigned short)(e & 0xFFFFu);
    }
    __syncthreads();

    // --- gather: wave w -> nodes w*8 .. w*8+7; quarter-wave per edge.
    int Q = lane >> 4;          // quarter: which edge in a group of 4
    int f = lane & 15;          // feature group: features 4f..4f+3

    for (int i = 0; i < 8; ++i) {
        int lrow = w * 8 + i;
        unsigned s0 = off_sh[lrow];
        unsigned dc = cnt_sh[lrow];
        unsigned e_end = s0 + dc;

        float a0 = 0.f, a1 = 0.f, a2 = 0.f, a3 = 0.f;
        for (unsigned b = s0; b < e_end; b += 8u) {
            unsigned i0 = b + (unsigned)Q;
            unsigned i1 = b + 4u + (unsigned)Q;
            unsigned src0 = (i0 < e_end) ? (unsigned)sorted_sh[i0] : 0u;
            unsigned src1 = (i1 < e_end) ? (unsigned)sorted_sh[i1] : 0u;
            ushort4 rv0 = *(const ushort4*)&x_bf16[(src0 << 6) + 4u * (unsigned)f];
            ushort4 rv1 = *(const ushort4*)&x_bf16[(src1 << 6) + 4u * (unsigned)f];
            if (i0 < e_end) {
                a0 += bf2f(rv0.x); a1 += bf2f(rv0.y);
                a2 += bf2f(rv0.z); a3 += bf2f(rv0.w);
            }
            if (i1 < e_end) {
                a0 += bf2f(rv1.x); a1 += bf2f(rv1.y);
                a2 += bf2f(rv1.z); a3 += bf2f(rv1.w);
            }
        }
        // reduce across quarters (lanes f, f+16, f+32, f+48)
        a0 += __shfl_xor(a0, 16); a1 += __shfl_xor(a1, 16);
        a2 += __shfl_xor(a2, 16); a3 += __shfl_xor(a3, 16);
        a0 += __shfl_xor(a0, 32); a1 += __shfl_xor(a1, 32);
        a2 += __shfl_xor(a2, 32); a3 += __shfl_xor(a3, 32);

        if (Q == 0) {
            float inv = dc ? 1.0f / (float)dc : 0.0f;
            uint2 p;
            p.x = pack2(a0 * inv, a1 * inv);
            p.y = pack2(a2 * inv, a3 * inv);
            *(uint2*)&A_sh[lrow * A_STRIDE + 64 + 4 * f] = p;
        }
    }
    __syncthreads();

    // --- MFMA: wave w -> m-rows 16*(w&3), n-tiles {2*(w>>2), 2*(w>>2)+1}
    int wm   = w & 3;
    int ng   = (w >> 2) * 2;
    int quad = lane >> 4;
    int l15  = lane & 15;

    f32x4 accr[2] = {{0.f,0.f,0.f,0.f},{0.f,0.f,0.f,0.f}};

    #pragma unroll
    for (int k0 = 0; k0 < 128; k0 += 32) {
        short8 a = *(const short8*)&A_sh[(16 * wm + l15) * A_STRIDE + k0 + quad * 8];
        #pragma unroll
        for (int t = 0; t < 2; ++t) {
            short8 b = *(const short8*)&B_sh[(16 * (ng + t) + l15) * A_STRIDE + k0 + quad * 8];
            accr[t] = __builtin_amdgcn_mfma_f32_16x16x32_bf16(a, b, accr[t], 0, 0, 0);
        }
    }

    #pragma unroll
    for (int t = 0; t < 2; ++t) {
        int col = (ng + t) * 16 + l15;
        float bs = b_self[col];
        float bm = b_msg[col];
        #pragma unroll
        for (int r = 0; r < 4; ++r) {
            int lrow = 16 * wm + quad * 4 + r;
            int grow = r0 + lrow;
            if (grow < N_NODES) {
                float vv = accr[t][r] + bs + (cnt_sh[lrow] > 0u ? bm : 0.0f);
                out[grow * D + col] = vv;
            }
        }
    }
}

// ---------------------------------------------------------------------------
extern "C" void kernel_launch(void* const* d_in, const int* in_sizes, int n_in,
                              void* d_out, int out_size, void* d_ws, size_t ws_size,
                              hipStream_t stream) {
    const float* x      = (const float*)d_in[0];
    const int*   edges  = (const int*)  d_in[1];
    const float* W_msg  = (const float*)d_in[2];
    const float* b_msg  = (const float*)d_in[3];
    const float* W_self = (const float*)d_in[4];
    const float* b_self = (const float*)d_in[5];
    float*       out    = (float*)d_out;

    // workspace layout (bytes), total ~10.5 MB
    char* ws = (char*)d_ws;
    unsigned*       cursor      = (unsigned*)(ws + 0);             // NB u32
    unsigned short* B_packed    = (unsigned short*)(ws + 4096);    // 16 KB
    unsigned*       bucket_data = (unsigned*)(ws + 20480);         // ~4 MB
    unsigned short* x_bf16      = (unsigned short*)(ws + 4030464); // 6.4 MB

    k_prep<<<512, 256, 0, stream>>>(x, x_bf16, W_msg, W_self, B_packed, cursor);
    k_bin_place<<<BIN_BLOCKS, 512, 0, stream>>>(edges, cursor, bucket_data);
    k_fused<<<NB, 512, 0, stream>>>(x_bf16, B_packed, b_msg, b_self,
                                    cursor, bucket_data, out);
}